// Round 1
// baseline (1151.781 us; speedup 1.0000x reference)
//
#include <hip/hip_runtime.h>
#include <math.h>

#define S_TOKENS 8192
#define D_DIM    1024
#define E_EXP    64
#define CAPACITY 256
#define TPB      32                 // tokens per gemm block
#define NBLK     (S_TOKENS / TPB)   // 256 gemm blocks
#define NZBLK    4096               // zero-fill blocks

// ---- d_out layout (float indices) ----
#define SZ_COMBINE   (134217728LL)                // 8192*64*256
#define OFF_COMBINE  (1LL)
#define OFF_DISPATCH (OFF_COMBINE + SZ_COMBINE)   // 134217729
#define OFF_EXPCNT   (OFF_DISPATCH + SZ_COMBINE)  // 268435457
#define OFF_ORGGATES (OFF_EXPCNT + E_EXP)         // 268435521

// ---- workspace layout (4-byte element indices) ----
#define WS_IDX1 0
#define WS_IDX2 (WS_IDX1 + S_TOKENS)
#define WS_G1   (WS_IDX2 + S_TOKENS)
#define WS_G2   (WS_G1 + S_TOKENS)
#define WS_CNT1 (WS_G2 + S_TOKENS)             // [NBLK][64] int
#define WS_CNT2 (WS_CNT1 + NBLK * E_EXP)
#define WS_OFF1 (WS_CNT2 + NBLK * E_EXP)       // exclusive scan of cnt1
#define WS_OFF2 (WS_OFF1 + NBLK * E_EXP)       // exclusive scan of cnt2 + total1
#define WS_MEP  (WS_OFF2 + NBLK * E_EXP)       // [NBLK][64] float partial sums of gates

// Kernel 1: blocks [0,NBLK): gate GEMM + softmax + top-2 argmax + histograms +
//           org_gates output.  blocks [NBLK, NBLK+NZBLK): zero-fill the
//           combine_weights/dispatch_mask region (and d_out[0]).
__global__ __launch_bounds__(256) void k1_gemm_gate(
    const float* __restrict__ x, const float* __restrict__ wg,
    float* __restrict__ out, int* __restrict__ wsi, float* __restrict__ wsf) {
  const int bid = blockIdx.x;
  const int tid = threadIdx.x;

  if (bid >= NBLK) {
    // ---- zero-fill: covers float indices [0, 2*SZ_COMBINE] inclusive ----
    float4 z = make_float4(0.f, 0.f, 0.f, 0.f);
    float4* p = (float4*)out;
    const size_t n4 = (size_t)(2 * SZ_COMBINE) / 4;  // 67108864, 16B aligned from base
    const size_t nth = (size_t)NZBLK * 256;
    for (size_t i = (size_t)(bid - NBLK) * 256 + tid; i < n4; i += nth) p[i] = z;
    if (bid == NBLK && tid == 0) out[2 * SZ_COMBINE] = 0.0f;  // last dispatch elem
    return;
  }

  __shared__ float xs[TPB][64];    // x tile
  __shared__ float wsh[64][64];    // wg tile
  __shared__ float Lg[TPB][65];    // logits, padded
  __shared__ float mM[TPB], rS[TPB];
  __shared__ int   li1[TPB], li2[TPB];
  __shared__ float mered[4][64];

  const int e  = tid & 63;   // expert owned by this lane
  const int tg = tid >> 6;   // token group 0..3 (== wave id)
  const int s0 = bid * TPB;

  float acc[8];
#pragma unroll
  for (int j = 0; j < 8; j++) acc[j] = 0.f;

  for (int k0 = 0; k0 < D_DIM; k0 += 64) {
    // stage x tile: 32 tokens x 64 k  (512 float4)
    for (int i = tid; i < TPB * 16; i += 256) {
      int t = i >> 4, c = i & 15;
      ((float4*)&xs[t][0])[c] =
          *(const float4*)&x[(size_t)(s0 + t) * D_DIM + k0 + 4 * c];
    }
    // stage wg tile: 64 k x 64 e  (1024 float4)
    for (int i = tid; i < 64 * 16; i += 256) {
      int kk = i >> 4, c = i & 15;
      ((float4*)&wsh[kk][0])[c] =
          *(const float4*)&wg[(size_t)(k0 + kk) * E_EXP + 4 * c];
    }
    __syncthreads();
#pragma unroll 8
    for (int kk = 0; kk < 64; kk++) {
      float w = wsh[kk][e];
#pragma unroll
      for (int j = 0; j < 8; j++)
        acc[j] = fmaf(xs[tg + 4 * j][kk], w, acc[j]);
    }
    __syncthreads();
  }

  // write logits to LDS
#pragma unroll
  for (int j = 0; j < 8; j++) Lg[tg + 4 * j][e] = acc[j];
  __syncthreads();

  // ---- per-token softmax + top-2 argmax, 8 threads per token ----
  {
    const int g = tid >> 3;  // token 0..31
    const int u = tid & 7;
    float bv = -INFINITY; int bi = 0;
#pragma unroll
    for (int i = 0; i < 8; i++) {
      int ee = u + 8 * i;
      float v = Lg[g][ee];
      if (v > bv) { bv = v; bi = ee; }   // strictly greater: first index wins
    }
#pragma unroll
    for (int d = 1; d < 8; d <<= 1) {
      float ov = __shfl_xor(bv, d, 8);
      int   oi = __shfl_xor(bi, d, 8);
      if (ov > bv || (ov == bv && oi < bi)) { bv = ov; bi = oi; }
    }
    const float m1 = bv; const int i1 = bi;

    float se = 0.f;
#pragma unroll
    for (int i = 0; i < 8; i++) se += expf(Lg[g][u + 8 * i] - m1);
#pragma unroll
    for (int d = 1; d < 8; d <<= 1) se += __shfl_xor(se, d, 8);

    // second argmax (exclude i1)
    float bv2 = -INFINITY; int bi2 = 0;
#pragma unroll
    for (int i = 0; i < 8; i++) {
      int ee = u + 8 * i;
      float v = Lg[g][ee];
      if (ee != i1 && v > bv2) { bv2 = v; bi2 = ee; }
    }
#pragma unroll
    for (int d = 1; d < 8; d <<= 1) {
      float ov = __shfl_xor(bv2, d, 8);
      int   oi = __shfl_xor(bi2, d, 8);
      if (ov > bv2 || (ov == bv2 && oi < bi2)) { bv2 = ov; bi2 = oi; }
    }

    if (u == 0) {
      float rs = 1.0f / se;
      mM[g] = m1; rS[g] = rs;
      li1[g] = i1; li2[g] = bi2;
      int s = s0 + g;
      wsi[WS_IDX1 + s] = i1;
      wsi[WS_IDX2 + s] = bi2;
      wsf[WS_G1 + s] = rs;                    // exp(m1-m1)/se
      wsf[WS_G2 + s] = expf(bv2 - m1) * rs;
    }
  }
  __syncthreads();

  // ---- org_gates output + me partial sums ----
  {
    float mes = 0.f;
#pragma unroll
    for (int j = 0; j < 8; j++) {
      int t = tg + 4 * j;
      float gate = expf(Lg[t][e] - mM[t]) * rS[t];
      out[OFF_ORGGATES + (size_t)(s0 + t) * E_EXP + e] = gate;
      mes += gate;
    }
    mered[tg][e] = mes;
  }
  __syncthreads();

  if (tid < 64) {
    wsf[WS_MEP + bid * 64 + tid] =
        mered[0][tid] + mered[1][tid] + mered[2][tid] + mered[3][tid];
    int c1 = 0, c2 = 0;
    for (int t = 0; t < TPB; t++) {
      c1 += (li1[t] == tid);
      c2 += (li2[t] == tid);
    }
    wsi[WS_CNT1 + bid * 64 + tid] = c1;
    wsi[WS_CNT2 + bid * 64 + tid] = c2;
  }
}

// Kernel 2: single block, thread e = expert.  Exclusive scan of per-chunk
// counts, exp_counts, l_aux.
__global__ __launch_bounds__(64) void k2_scan(
    float* __restrict__ out, int* __restrict__ wsi, float* __restrict__ wsf) {
  const int e = threadIdx.x;  // 0..63, one wave

  int run1 = 0;
#pragma unroll 8
  for (int c = 0; c < NBLK; c++) {
    int v = wsi[WS_CNT1 + c * 64 + e];
    wsi[WS_OFF1 + c * 64 + e] = run1;
    run1 += v;
  }
  const int total1 = run1;

  int run2 = total1;  // locations2 offset includes sum(mask1) per expert
#pragma unroll 8
  for (int c = 0; c < NBLK; c++) {
    int v = wsi[WS_CNT2 + c * 64 + e];
    wsi[WS_OFF2 + c * 64 + e] = run2;
    run2 += v;
  }
  const int total2 = run2 - total1;

  out[OFF_EXPCNT + e] = (float)(total1 + total2);

  float mesum = 0.f;
#pragma unroll 8
  for (int c = 0; c < NBLK; c++) mesum += wsf[WS_MEP + c * 64 + e];
  float me = mesum * (1.0f / 8192.0f);
  float ce = (float)total1 * (1.0f / 8192.0f);
  float prod = me * ce * 4096.0f;  // * E * E
#pragma unroll
  for (int d = 1; d < 64; d <<= 1) prod += __shfl_xor(prod, d, 64);
  if (e == 0) out[0] = prod;
}

// Kernel 3: per-chunk rank recompute + capacity drop + normalized-weight
// scatter into combine_weights / dispatch_mask.
__global__ __launch_bounds__(64) void k3_scatter(
    float* __restrict__ out, const int* __restrict__ wsi,
    const float* __restrict__ wsf) {
  __shared__ int li1[TPB], li2[TPB];
  const int bid = blockIdx.x;
  const int t = threadIdx.x;
  const int s0 = bid * TPB;

  if (t < TPB) {
    li1[t] = wsi[WS_IDX1 + s0 + t];
    li2[t] = wsi[WS_IDX2 + s0 + t];
  }
  __syncthreads();
  if (t >= TPB) return;

  const int e1 = li1[t], e2 = li2[t];
  int r1 = 0, r2 = 0;
  for (int j = 0; j < t; j++) {
    r1 += (li1[j] == e1);
    r2 += (li2[j] == e2);
  }
  const int loc1 = wsi[WS_OFF1 + bid * 64 + e1] + r1;
  const int loc2 = wsi[WS_OFF2 + bid * 64 + e2] + r2;
  const int s = s0 + t;

  const float g1r = wsf[WS_G1 + s];
  const float g2r = wsf[WS_G2 + s];
  const bool d1 = (loc1 >= CAPACITY);
  const bool d2 = (loc2 >= CAPACITY);
  const float g1f = d1 ? 0.f : g1r;
  const float g2f = d2 ? 0.f : g2r;
  const float denom = fmaxf(g1f + g2f, 1.1920929e-7f);  // finfo(f32).eps
  const float w1 = g1f / denom;
  const float w2 = g2f / denom;

  if (!d1) {
    size_t o = OFF_COMBINE + (size_t)s * (E_EXP * CAPACITY) +
               (size_t)e1 * CAPACITY + loc1;
    out[o] = w1;
    out[o + SZ_COMBINE] = (w1 != 0.f) ? 1.f : 0.f;
  }
  if (!d2) {
    size_t o = OFF_COMBINE + (size_t)s * (E_EXP * CAPACITY) +
               (size_t)e2 * CAPACITY + loc2;
    out[o] = w2;
    out[o + SZ_COMBINE] = (w2 != 0.f) ? 1.f : 0.f;
  }
}

extern "C" void kernel_launch(void* const* d_in, const int* in_sizes, int n_in,
                              void* d_out, int out_size, void* d_ws,
                              size_t ws_size, hipStream_t stream) {
  const float* x  = (const float*)d_in[0];
  const float* wg = (const float*)d_in[1];
  float* out = (float*)d_out;
  int*   wsi = (int*)d_ws;
  float* wsf = (float*)d_ws;

  hipLaunchKernelGGL(k1_gemm_gate, dim3(NBLK + NZBLK), dim3(256), 0, stream,
                     x, wg, out, wsi, wsf);
  hipLaunchKernelGGL(k2_scan, dim3(1), dim3(64), 0, stream, out, wsi, wsf);
  hipLaunchKernelGGL(k3_scatter, dim3(NBLK), dim3(64), 0, stream, out, wsi,
                     wsf);
}

// Round 2
// 1133.265 us; speedup vs baseline: 1.0163x; 1.0163x over previous
//
#include <hip/hip_runtime.h>
#include <math.h>

#define S_TOKENS 8192
#define D_DIM    1024
#define E_EXP    64
#define CAPACITY 256
#define TPB      32                 // tokens per gemm block
#define NBLK     (S_TOKENS / TPB)   // 256 gemm blocks
#define NZBLK    4096               // zero-fill blocks

// ---- d_out layout (float indices) ----
#define SZ_COMBINE   (134217728LL)                // 8192*64*256
#define OFF_COMBINE  (1LL)
#define OFF_DISPATCH (OFF_COMBINE + SZ_COMBINE)   // 134217729
#define OFF_EXPCNT   (OFF_DISPATCH + SZ_COMBINE)  // 268435457
#define OFF_ORGGATES (OFF_EXPCNT + E_EXP)         // 268435521

// ---- workspace layout (4-byte element indices) ----
#define WS_IDX1 0
#define WS_IDX2 (WS_IDX1 + S_TOKENS)
#define WS_G1   (WS_IDX2 + S_TOKENS)
#define WS_G2   (WS_G1 + S_TOKENS)
#define WS_CNT1 (WS_G2 + S_TOKENS)             // [NBLK][64] int   (16B-aligned)
#define WS_CNT2 (WS_CNT1 + NBLK * E_EXP)
#define WS_OFF1 (WS_CNT2 + NBLK * E_EXP)       // exclusive scan of cnt1
#define WS_OFF2 (WS_OFF1 + NBLK * E_EXP)       // exclusive scan of cnt2 + total1
#define WS_MEP  (WS_OFF2 + NBLK * E_EXP)       // [NBLK][64] float partial sums of gates

// Kernel 1: blocks [0,NBLK): gate GEMM + softmax + top-2 argmax + histograms +
//           org_gates output.  blocks [NBLK, NBLK+NZBLK): zero-fill the
//           combine_weights/dispatch_mask region (and d_out[0]).
__global__ __launch_bounds__(256) void k1_gemm_gate(
    const float* __restrict__ x, const float* __restrict__ wg,
    float* __restrict__ out, int* __restrict__ wsi, float* __restrict__ wsf) {
  const int bid = blockIdx.x;
  const int tid = threadIdx.x;

  if (bid >= NBLK) {
    // ---- zero-fill: covers float indices [0, 2*SZ_COMBINE) + last elem ----
    float4 z = make_float4(0.f, 0.f, 0.f, 0.f);
    float4* p = (float4*)out;
    const size_t n4 = (size_t)(2 * SZ_COMBINE) / 4;  // 67108864
    const size_t nth = (size_t)NZBLK * 256;
    for (size_t i = (size_t)(bid - NBLK) * 256 + tid; i < n4; i += nth) p[i] = z;
    if (bid == NBLK && tid == 0) out[2 * SZ_COMBINE] = 0.0f;  // last dispatch elem
    return;
  }

  __shared__ float xs[TPB][64];    // x tile
  __shared__ float wsh[64][64];    // wg tile
  __shared__ float Lg[TPB][65];    // logits, padded
  __shared__ float mM[TPB], rS[TPB];
  __shared__ int   li1[TPB], li2[TPB];
  __shared__ float mered[4][64];

  const int e  = tid & 63;   // expert owned by this lane
  const int tg = tid >> 6;   // token group 0..3 (== wave id)
  const int s0 = bid * TPB;

  float acc[8];
#pragma unroll
  for (int j = 0; j < 8; j++) acc[j] = 0.f;

  for (int k0 = 0; k0 < D_DIM; k0 += 64) {
    // stage x tile: 32 tokens x 64 k  (512 float4)
    for (int i = tid; i < TPB * 16; i += 256) {
      int t = i >> 4, c = i & 15;
      ((float4*)&xs[t][0])[c] =
          *(const float4*)&x[(size_t)(s0 + t) * D_DIM + k0 + 4 * c];
    }
    // stage wg tile: 64 k x 64 e  (1024 float4)
    for (int i = tid; i < 64 * 16; i += 256) {
      int kk = i >> 4, c = i & 15;
      ((float4*)&wsh[kk][0])[c] =
          *(const float4*)&wg[(size_t)(k0 + kk) * E_EXP + 4 * c];
    }
    __syncthreads();
#pragma unroll 8
    for (int kk = 0; kk < 64; kk++) {
      float w = wsh[kk][e];
#pragma unroll
      for (int j = 0; j < 8; j++)
        acc[j] = fmaf(xs[tg + 4 * j][kk], w, acc[j]);
    }
    __syncthreads();
  }

  // write logits to LDS
#pragma unroll
  for (int j = 0; j < 8; j++) Lg[tg + 4 * j][e] = acc[j];
  __syncthreads();

  // ---- per-token softmax + top-2 argmax, 8 threads per token ----
  {
    const int g = tid >> 3;  // token 0..31
    const int u = tid & 7;
    float bv = -INFINITY; int bi = 0;
#pragma unroll
    for (int i = 0; i < 8; i++) {
      int ee = u + 8 * i;
      float v = Lg[g][ee];
      if (v > bv) { bv = v; bi = ee; }   // strictly greater: first index wins
    }
#pragma unroll
    for (int d = 1; d < 8; d <<= 1) {
      float ov = __shfl_xor(bv, d, 8);
      int   oi = __shfl_xor(bi, d, 8);
      if (ov > bv || (ov == bv && oi < bi)) { bv = ov; bi = oi; }
    }
    const float m1 = bv; const int i1 = bi;

    float se = 0.f;
#pragma unroll
    for (int i = 0; i < 8; i++) se += expf(Lg[g][u + 8 * i] - m1);
#pragma unroll
    for (int d = 1; d < 8; d <<= 1) se += __shfl_xor(se, d, 8);

    // second argmax (exclude i1)
    float bv2 = -INFINITY; int bi2 = 0;
#pragma unroll
    for (int i = 0; i < 8; i++) {
      int ee = u + 8 * i;
      float v = Lg[g][ee];
      if (ee != i1 && v > bv2) { bv2 = v; bi2 = ee; }
    }
#pragma unroll
    for (int d = 1; d < 8; d <<= 1) {
      float ov = __shfl_xor(bv2, d, 8);
      int   oi = __shfl_xor(bi2, d, 8);
      if (ov > bv2 || (ov == bv2 && oi < bi2)) { bv2 = ov; bi2 = oi; }
    }

    if (u == 0) {
      float rs = 1.0f / se;
      mM[g] = m1; rS[g] = rs;
      li1[g] = i1; li2[g] = bi2;
      int s = s0 + g;
      wsi[WS_IDX1 + s] = i1;
      wsi[WS_IDX2 + s] = bi2;
      wsf[WS_G1 + s] = rs;                    // exp(m1-m1)/se
      wsf[WS_G2 + s] = expf(bv2 - m1) * rs;
    }
  }
  __syncthreads();

  // ---- org_gates output + me partial sums ----
  {
    float mes = 0.f;
#pragma unroll
    for (int j = 0; j < 8; j++) {
      int t = tg + 4 * j;
      float gate = expf(Lg[t][e] - mM[t]) * rS[t];
      out[OFF_ORGGATES + (size_t)(s0 + t) * E_EXP + e] = gate;
      mes += gate;
    }
    mered[tg][e] = mes;
  }
  __syncthreads();

  if (tid < 64) {
    wsf[WS_MEP + bid * 64 + tid] =
        mered[0][tid] + mered[1][tid] + mered[2][tid] + mered[3][tid];
    int c1 = 0, c2 = 0;
    for (int t = 0; t < TPB; t++) {
      c1 += (li1[t] == tid);
      c2 += (li2[t] == tid);
    }
    wsi[WS_CNT1 + bid * 64 + tid] = c1;
    wsi[WS_CNT2 + bid * 64 + tid] = c2;
  }
}

// Kernel 2: single block, 1024 threads.  Stage per-chunk counts into LDS
// (coalesced, no interleaved aliasing stores -> loads pipeline), then scan
// from LDS.  Also exp_counts + l_aux with parallel me reduction.
__global__ __launch_bounds__(1024) void k2_scan(
    float* __restrict__ out, int* __restrict__ wsi, float* __restrict__ wsf) {
  __shared__ int lc[NBLK * E_EXP];       // 64 KB, reused for cnt1 then cnt2
  __shared__ float mep[16][E_EXP];       // partial me sums
  __shared__ int tot1[E_EXP];

  const int tid = threadIdx.x;           // 0..1023

  // ---- parallel me partial sums: thread (cg,e) sums 16 chunks ----
  {
    const int e = tid & 63, cg = tid >> 6;     // cg in 0..15
    float s = 0.f;
#pragma unroll
    for (int c = cg * 16; c < cg * 16 + 16; c++)
      s += wsf[WS_MEP + c * 64 + e];
    mep[cg][e] = s;
  }

  // ---- stage cnt1 into LDS (4096 int4, coalesced) ----
  {
    const int4* g = (const int4*)&wsi[WS_CNT1];
    int4* l = (int4*)lc;
#pragma unroll
    for (int i = tid; i < NBLK * E_EXP / 4; i += 1024) l[i] = g[i];
  }
  __syncthreads();

  // ---- scan cnt1 (thread e = expert, reads LDS, stores global) ----
  if (tid < E_EXP) {
    int run = 0;
#pragma unroll 8
    for (int c = 0; c < NBLK; c++) {
      wsi[WS_OFF1 + c * 64 + tid] = run;
      run += lc[c * 64 + tid];
    }
    tot1[tid] = run;
  }
  __syncthreads();

  // ---- stage cnt2 into LDS ----
  {
    const int4* g = (const int4*)&wsi[WS_CNT2];
    int4* l = (int4*)lc;
#pragma unroll
    for (int i = tid; i < NBLK * E_EXP / 4; i += 1024) l[i] = g[i];
  }
  __syncthreads();

  if (tid < E_EXP) {
    const int e = tid;
    const int total1 = tot1[e];
    int run = total1;                    // locations2 offset includes sum(mask1)
#pragma unroll 8
    for (int c = 0; c < NBLK; c++) {
      wsi[WS_OFF2 + c * 64 + e] = run;
      run += lc[c * 64 + e];
    }
    const int total2 = run - total1;

    out[OFF_EXPCNT + e] = (float)(total1 + total2);

    float mesum = 0.f;
#pragma unroll
    for (int cg = 0; cg < 16; cg++) mesum += mep[cg][e];
    float me = mesum * (1.0f / 8192.0f);
    float ce = (float)total1 * (1.0f / 8192.0f);
    float prod = me * ce * 4096.0f;      // * E * E
#pragma unroll
    for (int d = 1; d < 64; d <<= 1) prod += __shfl_xor(prod, d, 64);
    if (e == 0) out[0] = prod;
  }
}

// Kernel 3: per-chunk rank recompute + capacity drop + normalized-weight
// scatter into combine_weights / dispatch_mask.
__global__ __launch_bounds__(64) void k3_scatter(
    float* __restrict__ out, const int* __restrict__ wsi,
    const float* __restrict__ wsf) {
  __shared__ int li1[TPB], li2[TPB];
  const int bid = blockIdx.x;
  const int t = threadIdx.x;
  const int s0 = bid * TPB;

  if (t < TPB) {
    li1[t] = wsi[WS_IDX1 + s0 + t];
    li2[t] = wsi[WS_IDX2 + s0 + t];
  }
  __syncthreads();
  if (t >= TPB) return;

  const int e1 = li1[t], e2 = li2[t];
  int r1 = 0, r2 = 0;
  for (int j = 0; j < t; j++) {
    r1 += (li1[j] == e1);
    r2 += (li2[j] == e2);
  }
  const int loc1 = wsi[WS_OFF1 + bid * 64 + e1] + r1;
  const int loc2 = wsi[WS_OFF2 + bid * 64 + e2] + r2;
  const int s = s0 + t;

  const float g1r = wsf[WS_G1 + s];
  const float g2r = wsf[WS_G2 + s];
  const bool d1 = (loc1 >= CAPACITY);
  const bool d2 = (loc2 >= CAPACITY);
  const float g1f = d1 ? 0.f : g1r;
  const float g2f = d2 ? 0.f : g2r;
  const float denom = fmaxf(g1f + g2f, 1.1920929e-7f);  // finfo(f32).eps
  const float w1 = g1f / denom;
  const float w2 = g2f / denom;

  if (!d1) {
    size_t o = OFF_COMBINE + (size_t)s * (E_EXP * CAPACITY) +
               (size_t)e1 * CAPACITY + loc1;
    out[o] = w1;
    out[o + SZ_COMBINE] = (w1 != 0.f) ? 1.f : 0.f;
  }
  if (!d2) {
    size_t o = OFF_COMBINE + (size_t)s * (E_EXP * CAPACITY) +
               (size_t)e2 * CAPACITY + loc2;
    out[o] = w2;
    out[o + SZ_COMBINE] = (w2 != 0.f) ? 1.f : 0.f;
  }
}

extern "C" void kernel_launch(void* const* d_in, const int* in_sizes, int n_in,
                              void* d_out, int out_size, void* d_ws,
                              size_t ws_size, hipStream_t stream) {
  const float* x  = (const float*)d_in[0];
  const float* wg = (const float*)d_in[1];
  float* out = (float*)d_out;
  int*   wsi = (int*)d_ws;
  float* wsf = (float*)d_ws;

  hipLaunchKernelGGL(k1_gemm_gate, dim3(NBLK + NZBLK), dim3(256), 0, stream,
                     x, wg, out, wsi, wsf);
  hipLaunchKernelGGL(k2_scan, dim3(1), dim3(1024), 0, stream, out, wsi, wsf);
  hipLaunchKernelGGL(k3_scatter, dim3(NBLK), dim3(64), 0, stream, out, wsi,
                     wsf);
}

// Round 3
// 1131.896 us; speedup vs baseline: 1.0176x; 1.0012x over previous
//
#include <hip/hip_runtime.h>
#include <math.h>

#define S_TOKENS 8192
#define D_DIM    1024
#define E_EXP    64
#define CAPACITY 256
#define TPB      64                 // tokens per gemm block
#define NBLK     (S_TOKENS / TPB)   // 128 gemm blocks
#define NZBLK    4096               // zero-fill blocks

typedef float fx4 __attribute__((ext_vector_type(4)));

// ---- d_out layout (float indices) ----
#define SZ_COMBINE   (134217728LL)                // 8192*64*256
#define OFF_COMBINE  (1LL)
#define OFF_DISPATCH (OFF_COMBINE + SZ_COMBINE)   // 134217729
#define OFF_EXPCNT   (OFF_DISPATCH + SZ_COMBINE)  // 268435457
#define OFF_ORGGATES (OFF_EXPCNT + E_EXP)         // 268435521 (== 1 mod 4 -> scalar stores only)

// ---- workspace layout (4-byte element indices) ----
#define WS_IDX1 0
#define WS_IDX2 (WS_IDX1 + S_TOKENS)
#define WS_G1   (WS_IDX2 + S_TOKENS)
#define WS_G2   (WS_G1 + S_TOKENS)
#define WS_CNT1 (WS_G2 + S_TOKENS)             // [NBLK][64] int (16B-aligned)
#define WS_CNT2 (WS_CNT1 + NBLK * E_EXP)
#define WS_OFF1 (WS_CNT2 + NBLK * E_EXP)       // exclusive scan of cnt1
#define WS_OFF2 (WS_OFF1 + NBLK * E_EXP)       // excl scan of cnt2 + total1
#define WS_MEP  (WS_OFF2 + NBLK * E_EXP)       // [NBLK][64] float partial me sums

// Kernel 1: blocks [0,NBLK): register-tiled gate GEMM (thread = 4 tokens x 4
// experts, b128 LDS reads) + softmax + top-2 + histograms + org_gates.
// Blocks [NBLK, NBLK+NZBLK): nontemporal zero-fill of combine/dispatch.
__global__ __launch_bounds__(256) void k1_gemm_gate(
    const float* __restrict__ x, const float* __restrict__ wg,
    float* __restrict__ out, int* __restrict__ wsi, float* __restrict__ wsf) {
  const int bid = blockIdx.x;
  const int tid = threadIdx.x;

  if (bid >= NBLK) {
    fx4 z = (fx4)0.f;
    fx4* p = (fx4*)out;
    const size_t n4 = (size_t)(2 * SZ_COMBINE) / 4;  // 67108864
    const size_t nth = (size_t)NZBLK * 256;
    for (size_t i = (size_t)(bid - NBLK) * 256 + tid; i < n4; i += nth)
      __builtin_nontemporal_store(z, &p[i]);
    if (bid == NBLK && tid == 0) out[2 * SZ_COMBINE] = 0.0f;  // last dispatch elem
    return;
  }

  __shared__ float xs[64][68];          // 64 tokens x 64 k, +4 pad (17.4 KB)
  __shared__ float ovl[64 * 68];        // overlay: wsh[64][64] then Lg[64][68]
  __shared__ float mM[64], rS[64];
  __shared__ int   li1[64], li2[64];
  __shared__ float mered[16][64];

  float (*wsh)[64] = (float(*)[64])ovl;
  float (*Lg)[68]  = (float(*)[68])ovl;

  const int tx = tid & 15;   // expert quad: experts 4*tx..4*tx+3
  const int ty = tid >> 4;   // token slot: tokens ty+16*i, i=0..3
  const int s0 = bid * TPB;

  float acc[4][4];
#pragma unroll
  for (int i = 0; i < 4; i++)
#pragma unroll
    for (int q = 0; q < 4; q++) acc[i][q] = 0.f;

  for (int k0 = 0; k0 < D_DIM; k0 += 64) {
    // stage x tile (64x64) and wg tile (64x64): 1024 float4 each
#pragma unroll
    for (int r = 0; r < 4; r++) {
      int i = tid + 256 * r;
      int t = i >> 4, c = i & 15;
      *(fx4*)&xs[t][4 * c] =
          *(const fx4*)&x[(size_t)(s0 + t) * D_DIM + k0 + 4 * c];
      *(fx4*)&wsh[t][4 * c] =
          *(const fx4*)&wg[(size_t)(k0 + t) * E_EXP + 4 * c];
    }
    __syncthreads();
    for (int kb = 0; kb < 64; kb += 4) {
      fx4 xa[4], wb[4];
#pragma unroll
      for (int i = 0; i < 4; i++) xa[i] = *(fx4*)&xs[ty + 16 * i][kb];
#pragma unroll
      for (int j = 0; j < 4; j++) wb[j] = *(fx4*)&wsh[kb + j][4 * tx];
#pragma unroll
      for (int j = 0; j < 4; j++)
#pragma unroll
        for (int i = 0; i < 4; i++) {
          float xv = xa[i][j];
#pragma unroll
          for (int q = 0; q < 4; q++)
            acc[i][q] = fmaf(xv, wb[j][q], acc[i][q]);
        }
    }
    __syncthreads();
  }

  // logits -> LDS (Lg overlays wsh; barrier above protects last reads)
#pragma unroll
  for (int i = 0; i < 4; i++) {
    fx4 v;
#pragma unroll
    for (int q = 0; q < 4; q++) v[q] = acc[i][q];
    *(fx4*)&Lg[ty + 16 * i][4 * tx] = v;
  }
  __syncthreads();

  // ---- per-token softmax + top-2 argmax, 4 threads per token ----
  {
    const int g = tid >> 2;  // token 0..63
    const int u = tid & 3;
    float bv = -INFINITY; int bi = 0;
#pragma unroll
    for (int i = 0; i < 16; i++) {
      int ee = u + 4 * i;
      float v = Lg[g][ee];
      if (v > bv) { bv = v; bi = ee; }
    }
#pragma unroll
    for (int d = 1; d < 4; d <<= 1) {
      float ovv = __shfl_xor(bv, d, 4);
      int   oi  = __shfl_xor(bi, d, 4);
      if (ovv > bv || (ovv == bv && oi < bi)) { bv = ovv; bi = oi; }
    }
    const float m1 = bv; const int i1 = bi;

    float se = 0.f;
#pragma unroll
    for (int i = 0; i < 16; i++) se += expf(Lg[g][u + 4 * i] - m1);
#pragma unroll
    for (int d = 1; d < 4; d <<= 1) se += __shfl_xor(se, d, 4);

    float bv2 = -INFINITY; int bi2 = 0;
#pragma unroll
    for (int i = 0; i < 16; i++) {
      int ee = u + 4 * i;
      float v = Lg[g][ee];
      if (ee != i1 && v > bv2) { bv2 = v; bi2 = ee; }
    }
#pragma unroll
    for (int d = 1; d < 4; d <<= 1) {
      float ovv = __shfl_xor(bv2, d, 4);
      int   oi  = __shfl_xor(bi2, d, 4);
      if (ovv > bv2 || (ovv == bv2 && oi < bi2)) { bv2 = ovv; bi2 = oi; }
    }

    if (u == 0) {
      float rs = 1.0f / se;
      mM[g] = m1; rS[g] = rs;
      li1[g] = i1; li2[g] = bi2;
      int s = s0 + g;
      wsi[WS_IDX1 + s] = i1;
      wsi[WS_IDX2 + s] = bi2;
      wsf[WS_G1 + s] = rs;                    // exp(m1-m1)/se
      wsf[WS_G2 + s] = expf(bv2 - m1) * rs;
    }
  }
  __syncthreads();

  // ---- org_gates output + me partial sums ----
  {
    float ms[4] = {0.f, 0.f, 0.f, 0.f};
#pragma unroll
    for (int i = 0; i < 4; i++) {
      int t = ty + 16 * i;
      float m = mM[t], r = rS[t];
      size_t ob = OFF_ORGGATES + (size_t)(s0 + t) * E_EXP + 4 * tx;
#pragma unroll
      for (int q = 0; q < 4; q++) {
        float gate = expf(Lg[t][4 * tx + q] - m) * r;
        out[ob + q] = gate;                   // region is 1 mod 4: scalar stores
        ms[q] += gate;
      }
    }
#pragma unroll
    for (int q = 0; q < 4; q++) mered[ty][4 * tx + q] = ms[q];
  }
  __syncthreads();

  if (tid < 64) {
    float s = 0.f;
#pragma unroll
    for (int yy = 0; yy < 16; yy++) s += mered[yy][tid];
    wsf[WS_MEP + bid * 64 + tid] = s;
    int c1 = 0, c2 = 0;
    for (int t = 0; t < TPB; t++) {
      c1 += (li1[t] == tid);
      c2 += (li2[t] == tid);
    }
    wsi[WS_CNT1 + bid * 64 + tid] = c1;
    wsi[WS_CNT2 + bid * 64 + tid] = c2;
  }
}

// Kernel 2: single block, 1024 threads.  LDS-staged scans + exp_counts + l_aux.
__global__ __launch_bounds__(1024) void k2_scan(
    float* __restrict__ out, int* __restrict__ wsi, float* __restrict__ wsf) {
  __shared__ int lc[NBLK * E_EXP];       // 32 KB, reused cnt1 then cnt2
  __shared__ float mep[16][E_EXP];
  __shared__ int tot1[E_EXP];

  const int tid = threadIdx.x;

  {
    const int e = tid & 63, cg = tid >> 6;     // cg 0..15, 8 chunks each
    float s = 0.f;
#pragma unroll
    for (int c = cg * 8; c < cg * 8 + 8; c++) s += wsf[WS_MEP + c * 64 + e];
    mep[cg][e] = s;
  }

  {
    const int4* g = (const int4*)&wsi[WS_CNT1];
    int4* l = (int4*)lc;
#pragma unroll
    for (int i = tid; i < NBLK * E_EXP / 4; i += 1024) l[i] = g[i];
  }
  __syncthreads();

  if (tid < E_EXP) {
    int run = 0;
#pragma unroll 8
    for (int c = 0; c < NBLK; c++) {
      wsi[WS_OFF1 + c * 64 + tid] = run;
      run += lc[c * 64 + tid];
    }
    tot1[tid] = run;
  }
  __syncthreads();

  {
    const int4* g = (const int4*)&wsi[WS_CNT2];
    int4* l = (int4*)lc;
#pragma unroll
    for (int i = tid; i < NBLK * E_EXP / 4; i += 1024) l[i] = g[i];
  }
  __syncthreads();

  if (tid < E_EXP) {
    const int e = tid;
    const int total1 = tot1[e];
    int run = total1;
#pragma unroll 8
    for (int c = 0; c < NBLK; c++) {
      wsi[WS_OFF2 + c * 64 + e] = run;
      run += lc[c * 64 + e];
    }
    const int total2 = run - total1;

    out[OFF_EXPCNT + e] = (float)(total1 + total2);

    float mesum = 0.f;
#pragma unroll
    for (int cg = 0; cg < 16; cg++) mesum += mep[cg][e];
    float me = mesum * (1.0f / 8192.0f);
    float ce = (float)total1 * (1.0f / 8192.0f);
    float prod = me * ce * 4096.0f;      // * E * E
#pragma unroll
    for (int d = 1; d < 64; d <<= 1) prod += __shfl_xor(prod, d, 64);
    if (e == 0) out[0] = prod;
  }
}

// Kernel 3: per-chunk rank recompute + capacity drop + scatter.
__global__ __launch_bounds__(64) void k3_scatter(
    float* __restrict__ out, const int* __restrict__ wsi,
    const float* __restrict__ wsf) {
  __shared__ int li1[TPB], li2[TPB];
  const int bid = blockIdx.x;
  const int t = threadIdx.x;
  const int s0 = bid * TPB;

  li1[t] = wsi[WS_IDX1 + s0 + t];
  li2[t] = wsi[WS_IDX2 + s0 + t];
  __syncthreads();

  const int e1 = li1[t], e2 = li2[t];
  int r1 = 0, r2 = 0;
  for (int j = 0; j < t; j++) {
    r1 += (li1[j] == e1);
    r2 += (li2[j] == e2);
  }
  const int loc1 = wsi[WS_OFF1 + bid * 64 + e1] + r1;
  const int loc2 = wsi[WS_OFF2 + bid * 64 + e2] + r2;
  const int s = s0 + t;

  const float g1r = wsf[WS_G1 + s];
  const float g2r = wsf[WS_G2 + s];
  const bool d1 = (loc1 >= CAPACITY);
  const bool d2 = (loc2 >= CAPACITY);
  const float g1f = d1 ? 0.f : g1r;
  const float g2f = d2 ? 0.f : g2r;
  const float denom = fmaxf(g1f + g2f, 1.1920929e-7f);  // finfo(f32).eps
  const float w1 = g1f / denom;
  const float w2 = g2f / denom;

  if (!d1) {
    size_t o = OFF_COMBINE + (size_t)s * (E_EXP * CAPACITY) +
               (size_t)e1 * CAPACITY + loc1;
    out[o] = w1;
    out[o + SZ_COMBINE] = (w1 != 0.f) ? 1.f : 0.f;
  }
  if (!d2) {
    size_t o = OFF_COMBINE + (size_t)s * (E_EXP * CAPACITY) +
               (size_t)e2 * CAPACITY + loc2;
    out[o] = w2;
    out[o + SZ_COMBINE] = (w2 != 0.f) ? 1.f : 0.f;
  }
}

extern "C" void kernel_launch(void* const* d_in, const int* in_sizes, int n_in,
                              void* d_out, int out_size, void* d_ws,
                              size_t ws_size, hipStream_t stream) {
  const float* x  = (const float*)d_in[0];
  const float* wg = (const float*)d_in[1];
  float* out = (float*)d_out;
  int*   wsi = (int*)d_ws;
  float* wsf = (float*)d_ws;

  hipLaunchKernelGGL(k1_gemm_gate, dim3(NBLK + NZBLK), dim3(256), 0, stream,
                     x, wg, out, wsi, wsf);
  hipLaunchKernelGGL(k2_scan, dim3(1), dim3(1024), 0, stream, out, wsi, wsf);
  hipLaunchKernelGGL(k3_scatter, dim3(NBLK), dim3(64), 0, stream, out, wsi,
                     wsf);
}